// Round 4
// baseline (263.017 us; speedup 1.0000x reference)
//
#include <hip/hip_runtime.h>
#include <math.h>

#define NATOMS 4096
#define R_CUT 5.0f
#define BLOCK 256
#define DISP_F4_PER_ROW (NATOMS * 3 / 4)   // 3072 float4 per disp row
#define MASK_F4_PER_ROW (NATOMS / 4)       // 1024 float4 per mask row

// Wave-uniform binary searches over the sorted batch array.
__device__ __forceinline__ int lower_bound_i(const int* __restrict__ b, int n, int v) {
    int lo = 0, hi = n;
    while (lo < hi) { int mid = (lo + hi) >> 1; if (b[mid] < v) lo = mid + 1; else hi = mid; }
    return lo;
}
__device__ __forceinline__ int upper_bound_i(const int* __restrict__ b, int n, int v) {
    int lo = 0, hi = n;
    while (lo < hi) { int mid = (lo + hi) >> 1; if (b[mid] <= v) lo = mid + 1; else hi = mid; }
    return lo;
}

// Computes wrapped displacement + edge flag for pair (i,j). Exact numpy
// evaluation order (no fma contraction) so the mask compare is bit-stable.
// Returns zeros when not an edge / out of band / self.
__device__ __forceinline__ void pair_disp(
    int j, int i, int g0, int g1,
    float pix, float piy, float piz,
    const float* __restrict__ pos,
    float A00, float A01, float A02, float A10, float A11, float A12,
    float A20, float A21, float A22,
    float C00, float C01, float C02, float C10, float C11, float C12,
    float C20, float C21, float C22,
    float& o0, float& o1, float& o2, bool& m)
{
    o0 = 0.0f; o1 = 0.0f; o2 = 0.0f; m = false;
    if (j < g0 || j >= g1 || j == i) return;

    const float d0 = __fsub_rn(pix, pos[j * 3 + 0]);
    const float d1 = __fsub_rn(piy, pos[j * 3 + 1]);
    const float d2 = __fsub_rn(piz, pos[j * 3 + 2]);

    const float s0 = __fadd_rn(__fadd_rn(__fmul_rn(A00, d0), __fmul_rn(A01, d1)), __fmul_rn(A02, d2));
    const float s1 = __fadd_rn(__fadd_rn(__fmul_rn(A10, d0), __fmul_rn(A11, d1)), __fmul_rn(A12, d2));
    const float s2 = __fadd_rn(__fadd_rn(__fmul_rn(A20, d0), __fmul_rn(A21, d1)), __fmul_rn(A22, d2));

    const float r0 = rintf(s0);   // round-half-even == jnp.round
    const float r1 = rintf(s1);
    const float r2 = rintf(s2);

    const float w0 = __fsub_rn(d0, __fadd_rn(__fadd_rn(__fmul_rn(C00, r0), __fmul_rn(C01, r1)), __fmul_rn(C02, r2)));
    const float w1 = __fsub_rn(d1, __fadd_rn(__fadd_rn(__fmul_rn(C10, r0), __fmul_rn(C11, r1)), __fmul_rn(C12, r2)));
    const float w2 = __fsub_rn(d2, __fadd_rn(__fadd_rn(__fmul_rn(C20, r0), __fmul_rn(C21, r1)), __fmul_rn(C22, r2)));

    const float n2 = __fadd_rn(__fadd_rn(__fmul_rn(w0, w0), __fmul_rn(w1, w1)), __fmul_rn(w2, w2));
    if (sqrtf(n2) < R_CUT) {
        m = true; o0 = w0; o1 = w1; o2 = w2;
    }
}

// One block per row i. Dense lane-contiguous float4 stores over BOTH the
// disp row (3072 f4) and mask row (1024 f4). A disp float4 at index f covers
// exactly two atoms j0=(4f)/3 and j0+1; the storing thread computes those
// pairs itself (no LDS transpose needed). Out-of-band float4s are pure zero
// stores — ~87.5% of the traffic runs at fill rate.
__global__ __launch_bounds__(BLOCK) void radius_graph_dense_kernel(
    const float* __restrict__ pos,    // [N,3]
    const float* __restrict__ cell,   // [B,3,3]
    const int*   __restrict__ batch,  // [N]
    float* __restrict__ disp_out,     // [N,N,3]
    float* __restrict__ mask_out)     // [N,N] as 0/1 float
{
    const int i   = blockIdx.x;
    const int tid = (int)threadIdx.x;

    // Wave-uniform row data (scalar-unit friendly).
    const int bi = batch[i];
    const float pix = pos[i * 3 + 0];
    const float piy = pos[i * 3 + 1];
    const float piz = pos[i * 3 + 2];

    const float* C = cell + bi * 9;
    const float C00 = C[0], C01 = C[1], C02 = C[2];
    const float C10 = C[3], C11 = C[4], C12 = C[5];
    const float C20 = C[6], C21 = C[7], C22 = C[8];
    // A = inv(C^T) = cofactor(C) / det(C)
    const float cof00 =  (C11 * C22 - C12 * C21);
    const float cof01 = -(C10 * C22 - C12 * C20);
    const float cof02 =  (C10 * C21 - C11 * C20);
    const float cof10 = -(C01 * C22 - C02 * C21);
    const float cof11 =  (C00 * C22 - C02 * C20);
    const float cof12 = -(C00 * C21 - C01 * C20);
    const float cof20 =  (C01 * C12 - C02 * C11);
    const float cof21 = -(C00 * C12 - C02 * C10);
    const float cof22 =  (C00 * C11 - C01 * C10);
    const float det = C00 * cof00 + C01 * cof01 + C02 * cof02;
    const float id  = 1.0f / det;
    const float A00 = cof00 * id, A01 = cof01 * id, A02 = cof02 * id;
    const float A10 = cof10 * id, A11 = cof11 * id, A12 = cof12 * id;
    const float A20 = cof20 * id, A21 = cof21 * id, A22 = cof22 * id;

    // Same-graph column range (batch sorted): j in [g0,g1) <=> batch[j]==bi.
    const int g0 = lower_bound_i(batch, NATOMS, bi);
    const int g1 = upper_bound_i(batch, NATOMS, bi);

    float4* __restrict__ drow = (float4*)(disp_out + (size_t)i * (NATOMS * 3));
    float4* __restrict__ mrow = (float4*)(mask_out + (size_t)i * NATOMS);

    // ---- disp region: 3072 float4, 12 per thread, lane-contiguous ----
    #pragma unroll 4
    for (int s = 0; s < DISP_F4_PER_ROW / BLOCK; ++s) {
        const int f  = tid + s * BLOCK;
        const int fb = f * 4;            // first float index in row
        const int j0 = fb / 3;           // first atom this float4 touches
        const int r  = fb - j0 * 3;      // component offset 0..2
        const int j1 = j0 + 1;           // second (and last) atom touched

        float4 v = make_float4(0.0f, 0.0f, 0.0f, 0.0f);
        if (j1 >= g0 && j0 < g1) {
            float a0, a1, a2, b0, b1, b2; bool ma, mb;
            pair_disp(j0, i, g0, g1, pix, piy, piz, pos,
                      A00, A01, A02, A10, A11, A12, A20, A21, A22,
                      C00, C01, C02, C10, C11, C12, C20, C21, C22,
                      a0, a1, a2, ma);
            pair_disp(j1, i, g0, g1, pix, piy, piz, pos,
                      A00, A01, A02, A10, A11, A12, A20, A21, A22,
                      C00, C01, C02, C10, C11, C12, C20, C21, C22,
                      b0, b1, b2, mb);
            if (r == 0)      v = make_float4(a0, a1, a2, b0);
            else if (r == 1) v = make_float4(a1, a2, b0, b1);
            else             v = make_float4(a2, b0, b1, b2);
        }
        drow[f] = v;
    }

    // ---- mask region: 1024 float4, 4 per thread, lane-contiguous ----
    #pragma unroll
    for (int s = 0; s < MASK_F4_PER_ROW / BLOCK; ++s) {
        const int f     = tid + s * BLOCK;
        const int jbase = f * 4;
        float4 mv = make_float4(0.0f, 0.0f, 0.0f, 0.0f);
        if (jbase + 3 >= g0 && jbase < g1) {
            float* mvp = (float*)&mv;
            #pragma unroll
            for (int e = 0; e < 4; ++e) {
                float o0, o1, o2; bool m;
                pair_disp(jbase + e, i, g0, g1, pix, piy, piz, pos,
                          A00, A01, A02, A10, A11, A12, A20, A21, A22,
                          C00, C01, C02, C10, C11, C12, C20, C21, C22,
                          o0, o1, o2, m);
                mvp[e] = m ? 1.0f : 0.0f;
            }
        }
        mrow[f] = mv;
    }
}

extern "C" void kernel_launch(void* const* d_in, const int* in_sizes, int n_in,
                              void* d_out, int out_size, void* d_ws, size_t ws_size,
                              hipStream_t stream) {
    const float* pos   = (const float*)d_in[0];
    const float* cell  = (const float*)d_in[1];
    const int*   batch = (const int*)d_in[2];

    float* disp_out = (float*)d_out;
    float* mask_out = (float*)d_out + (size_t)NATOMS * NATOMS * 3;

    radius_graph_dense_kernel<<<NATOMS, BLOCK, 0, stream>>>(
        pos, cell, batch, disp_out, mask_out);
}